// Round 9
// baseline (86.929 us; speedup 1.0000x reference)
//
#include <hip/hip_runtime.h>

// out[b] = P @ X[b] @ P^T, P (7140x1024) 0/1 with one 1 per column => scatter:
// out[b][rank(i)][rank(j)] = X[b][i][j], zeros elsewhere.
// SINGLE one-shot kernel in the R5-A fill shape (fastest custom store loop:
// 24,893 blocks x 256 threads x 4 strided 16B stores over a contiguous 16KB
// region). Rows are vec-aligned (7140/4=1785) so each block spans 1-2 rows,
// known scalarly; blocks with no data row run the pure fill path; blocks
// touching a data row build the shared inv LUT in LDS and substitute gathered
// source values into the same stores. Output written exactly once (408 MB).

constexpr int D_IN  = 1024;
constexpr int D_OUT = 7140;             // C(36,3)
constexpr int VROW  = D_OUT / 4;        // 1785 f32x4 per output row
constexpr long long VTOT = 2LL * D_OUT * VROW;   // 25,489,800 vecs

typedef float f32x4 __attribute__((ext_vector_type(4)));

// rank of (a,b,c), 0<=a<b<c<36, among C(36,3) combos (closed form, verified R5-R8)
__device__ __forceinline__ int rank36_3(int a, int b, int c) {
    int s1 = 7140 - (36 - a) * (35 - a) * (34 - a) / 6;
    int s2 = ((34 - a) * (35 - a) - (35 - b) * (36 - b)) / 2;
    return s1 + s2 + (c - b - 1);
}

// unrank o in [0,7140) -> combination a<b<c
__device__ __forceinline__ void unrank36_3(int o, int& a, int& b, int& c) {
    int r = o; a = 0;
    for (;;) { int cnt = (35 - a) * (34 - a) / 2; if (r < cnt) break; r -= cnt; ++a; }
    b = a + 1;
    for (;;) { int cnt = 35 - b; if (r < cnt) break; r -= cnt; ++b; }
    c = b + 1 + r;
}

// row index (0..14279) -> source row t (0..1023) if data row, else -1
__device__ __forceinline__ int data_src_row(int row) {
    int a, b, c;
    unrank36_3(row >= D_OUT ? row - D_OUT : row, a, b, c);
    if (a < 16 && b >= 16 && b < 32 && c >= 32)
        return ((a * 16 + (b - 16)) << 2) + (c - 32);
    return -1;
}

__global__ __launch_bounds__(256) void fused_fill_scatter_kernel(
    const float* __restrict__ in, float* __restrict__ out)
{
    __shared__ __align__(16) short inv[D_OUT];   // output col -> source col, or -1

    const long long B0 = (long long)blockIdx.x * 1024;       // first vec of block
    const long long Bend = B0 + 1023 < VTOT - 1 ? B0 + 1023 : VTOT - 1;
    const int r0 = (int)(B0 / VROW);                          // first row touched
    const int r1 = (int)(Bend / VROW);                        // last row touched

    const int t0 = data_src_row(r0);
    const int t1 = (r1 != r0) ? data_src_row(r1) : -1;

    f32x4* __restrict__ ov = reinterpret_cast<f32x4*>(out);
    const f32x4 z = (f32x4)(0.f);
    const long long i0 = B0 + threadIdx.x;

    if (t0 < 0 && t1 < 0) {                // pure fill path (~78% of blocks)
        if (B0 + 1024 <= VTOT) {
            ov[i0] = z; ov[i0 + 256] = z; ov[i0 + 512] = z; ov[i0 + 768] = z;
        } else {
            #pragma unroll
            for (int k = 0; k < 4; ++k) { long long i = i0 + k * 256; if (i < VTOT) ov[i] = z; }
        }
        return;
    }

    // data path: build shared LUT (row-independent)
    for (int q = threadIdx.x; q < D_OUT; q += 256) inv[q] = -1;
    __syncthreads();
    for (int q = threadIdx.x; q < D_IN; q += 256) {
        int ch = q & 3, col = (q >> 2) & 15, line = q >> 6;
        inv[rank36_3(line, 16 + col, 32 + ch)] = (short)q;
    }
    __syncthreads();

    const float* __restrict__ src0 = (t0 >= 0)
        ? in + (size_t)(r0 >= D_OUT) * (D_IN * D_IN) + (size_t)t0 * D_IN : nullptr;
    const float* __restrict__ src1 = (t1 >= 0)
        ? in + (size_t)(r1 >= D_OUT) * (D_IN * D_IN) + (size_t)t1 * D_IN : nullptr;

    const long long rowB   = (long long)(r0 + 1) * VROW;   // vec boundary r0|r1
    const long long base0  = (long long)r0 * VROW;

    #pragma unroll
    for (int k = 0; k < 4; ++k) {
        long long i = i0 + k * 256;
        if (i >= VTOT) continue;
        const bool inR1 = (i >= rowB);
        const float* __restrict__ sp = inR1 ? src1 : src0;
        f32x4 v = z;
        if (sp) {
            int pv = (int)(i - (inR1 ? rowB : base0));     // vec index within row
            short4 iv = *reinterpret_cast<const short4*>(&inv[pv * 4]);
            if (iv.x >= 0) v.x = sp[iv.x];
            if (iv.y >= 0) v.y = sp[iv.y];
            if (iv.z >= 0) v.z = sp[iv.z];
            if (iv.w >= 0) v.w = sp[iv.w];
        }
        ov[i] = v;
    }
}

extern "C" void kernel_launch(void* const* d_in, const int* in_sizes, int n_in,
                              void* d_out, int out_size, void* d_ws, size_t ws_size,
                              hipStream_t stream) {
    const float* in = (const float*)d_in[0];   // (2, 1024, 1024) f32
    float* out = (float*)d_out;                // (2, 7140, 7140) f32

    int grid = (int)((VTOT + 1023) / 1024);    // 24,893 one-shot blocks
    hipLaunchKernelGGL(fused_fill_scatter_kernel, dim3(grid), dim3(256), 0, stream,
                       in, out);
}

// Round 10
// 76.313 us; speedup vs baseline: 1.1391x; 1.1391x over previous
//
#include <hip/hip_runtime.h>

// out[b] = P @ X[b] @ P^T, P (7140x1024) 0/1 with one 1 per column => scatter:
// out[b][rank(i)][rank(j)] = X[b][i][j], zeros elsewhere.
// hipMemsetAsync zero-fills 408MB at rocclr fill speed; then a minimal
// full-row writer rewrites the 2048 data rows. The column LUT inv[7140]
// (output col -> source col or -1) is built at COMPILE TIME into __constant__
// memory — R8's writer spent 82% of its rounds rebuilding it per block.

constexpr int D_IN  = 1024;
constexpr int D_OUT = 7140;            // C(36,3)
constexpr int VROW  = D_OUT / 4;       // 1785 f32x4 per output row

typedef float f32x4 __attribute__((ext_vector_type(4)));

// rank of (a,b,c), 0<=a<b<c<36, among C(36,3) combos (closed form, verified R5-R9)
__device__ __forceinline__ int rank36_3(int a, int b, int c) {
    int s1 = 7140 - (36 - a) * (35 - a) * (34 - a) / 6;
    int s2 = ((34 - a) * (35 - a) - (35 - b) * (36 - b)) / 2;
    return s1 + s2 + (c - b - 1);
}

// Compile-time inverse LUT (same loop formula verified exact since R1).
struct alignas(16) InvLut { short v[D_OUT]; };
constexpr InvLut make_inv() {
    InvLut L{};
    for (int i = 0; i < D_OUT; ++i) L.v[i] = -1;
    for (int t = 0; t < D_IN; ++t) {
        int ch = t & 3, col = (t >> 2) & 15, line = t >> 6;
        int a = line, b = 16 + col, c = 32 + ch;
        int r = 0;
        for (int x = 0; x < a; ++x) r += (35 - x) * (34 - x) / 2;
        for (int y = a + 1; y < b; ++y) r += 35 - y;
        r += c - b - 1;
        L.v[r] = (short)t;
    }
    return L;
}
__constant__ InvLut INV = make_inv();

// one block per (batch, source row): stage 4KB row in LDS, write full output row
__global__ __launch_bounds__(256) void row_writer_kernel(
    const float* __restrict__ in, float* __restrict__ out)
{
    __shared__ __align__(16) float srow[D_IN];

    const int bb = blockIdx.x >> 10;             // batch
    const int t  = blockIdx.x & 1023;            // source row index

    // stage source row (256 lanes x 16B, coalesced)
    reinterpret_cast<f32x4*>(srow)[threadIdx.x] =
        reinterpret_cast<const f32x4*>(in + (size_t)bb * (D_IN * D_IN)
                                          + (size_t)t * D_IN)[threadIdx.x];

    const int o = rank36_3(t >> 6, 16 + ((t >> 2) & 15), 32 + (t & 3));
    f32x4* __restrict__ orow =
        reinterpret_cast<f32x4*>(out) + (size_t)((size_t)bb * D_OUT + o) * VROW;
    __syncthreads();

    for (int p = threadIdx.x; p < VROW; p += 256) {
        short4 iv = *reinterpret_cast<const short4*>(&INV.v[p * 4]);
        f32x4 v;
        v.x = (iv.x >= 0) ? srow[iv.x] : 0.f;
        v.y = (iv.y >= 0) ? srow[iv.y] : 0.f;
        v.z = (iv.z >= 0) ? srow[iv.z] : 0.f;
        v.w = (iv.w >= 0) ? srow[iv.w] : 0.f;
        orow[p] = v;
    }
}

extern "C" void kernel_launch(void* const* d_in, const int* in_sizes, int n_in,
                              void* d_out, int out_size, void* d_ws, size_t ws_size,
                              hipStream_t stream) {
    const float* in = (const float*)d_in[0];   // (2, 1024, 1024) f32
    float* out = (float*)d_out;                // (2, 7140, 7140) f32

    // zero-fill at rocclr fill speed (graph-capturable memset node)
    hipMemsetAsync(out, 0, (size_t)out_size * sizeof(float), stream);

    hipLaunchKernelGGL(row_writer_kernel, dim3(2 * D_IN), dim3(256), 0, stream,
                       in, out);
}